// Round 1
// baseline (116.199 us; speedup 1.0000x reference)
//
#include <hip/hip_runtime.h>

#define BB 256
#define TT 32
#define DD 256
#define HH 256

// ws layout:
//   ax   : float4[BB*TT]   offset 0       (131072 B)  {f,i,g,o} pre-activations
//   hseq : float[BB*TT]    offset 131072  (32768 B)
//   hfin : float[BB]       offset 163840  (1024 B)
//   cfin : float[BB]       offset 164864  (1024 B)

// Kernel 1: ax[b,t,g] = x[b,t,:] . W_g[0,0:D] + b_g[0]
// one wave per (b,t) row; lane i handles float4 i of the 256-float row.
__global__ __launch_bounds__(256) void qlstm_gemv(
    const float* __restrict__ x,
    const float* __restrict__ Wf, const float* __restrict__ bf,
    const float* __restrict__ Wi, const float* __restrict__ bi,
    const float* __restrict__ Wg, const float* __restrict__ bg,
    const float* __restrict__ Wo, const float* __restrict__ bo,
    float4* __restrict__ ax)
{
    const int tid  = threadIdx.x;
    const int lane = tid & 63;
    const int wave = tid >> 6;
    const int row  = blockIdx.x * 4 + wave;   // row = b*TT + t, in [0, BB*TT)

    const float4 xv = reinterpret_cast<const float4*>(x + row * DD)[lane];
    const float4 wf = reinterpret_cast<const float4*>(Wf)[lane];  // W row 0, first 256
    const float4 wi = reinterpret_cast<const float4*>(Wi)[lane];
    const float4 wg = reinterpret_cast<const float4*>(Wg)[lane];
    const float4 wo = reinterpret_cast<const float4*>(Wo)[lane];

    float sf = xv.x*wf.x + xv.y*wf.y + xv.z*wf.z + xv.w*wf.w;
    float si = xv.x*wi.x + xv.y*wi.y + xv.z*wi.z + xv.w*wi.w;
    float sg = xv.x*wg.x + xv.y*wg.y + xv.z*wg.z + xv.w*wg.w;
    float so = xv.x*wo.x + xv.y*wo.y + xv.z*wo.z + xv.w*wo.w;

    #pragma unroll
    for (int off = 32; off > 0; off >>= 1) {
        sf += __shfl_down(sf, off);
        si += __shfl_down(si, off);
        sg += __shfl_down(sg, off);
        so += __shfl_down(so, off);
    }
    if (lane == 0)
        ax[row] = make_float4(sf + bf[0], si + bi[0], sg + bg[0], so + bo[0]);
}

// Kernel 2: LSTM scan. 4 lanes per batch element, one gate each.
// gate value = act( cos(rx0 + ax + h*wh) * K ),  K = (1 + sum_w prod_{j<=w} cos(rx_j))/8
__global__ __launch_bounds__(256) void qlstm_scan(
    const float* __restrict__ Wf, const float* __restrict__ rxf,
    const float* __restrict__ Wi, const float* __restrict__ rxi,
    const float* __restrict__ Wg, const float* __restrict__ rxg,
    const float* __restrict__ Wo, const float* __restrict__ rxo,
    const float* __restrict__ ax,
    float* __restrict__ hseq, float* __restrict__ hfin, float* __restrict__ cfin)
{
    __shared__ float red[256];
    __shared__ float sWh[4], sK[4], sRx0[4];
    const int tid = threadIdx.x;

    const float* Ws[4]  = {Wf, Wi, Wg, Wo};
    const float* rxs[4] = {rxf, rxi, rxg, rxo};

    // wh_g = sum of W_g[0, D:D+H]  (h is uniform across hidden columns)
    for (int g = 0; g < 4; ++g) {
        red[tid] = Ws[g][DD + tid];
        __syncthreads();
        for (int s = 128; s > 0; s >>= 1) {
            if (tid < s) red[tid] += red[tid + s];
            __syncthreads();
        }
        if (tid == 0) sWh[g] = red[0];
        __syncthreads();
    }
    if (tid < 4) {
        const float* rx = rxs[tid];
        float acc = 0.f;                     // Horner: A_k = z_k*(1+A_{k+1})
        for (int j = 7; j >= 1; --j) acc = cosf(rx[j]) * (1.f + acc);
        sK[tid]   = (1.f + acc) * 0.125f;
        sRx0[tid] = rx[0];
    }
    __syncthreads();

    const int g     = tid & 3;
    const int b     = blockIdx.x * 64 + (tid >> 2);
    const int lane  = tid & 63;
    const int gbase = lane & ~3;
    const float wh  = sWh[g], K = sK[g], rx0 = sRx0[g];

    float h = 0.f, c = 0.f;
    for (int t = 0; t < TT; ++t) {
        const float a  = ax[(b * TT + t) * 4 + g];
        const float v  = cosf(rx0 + a + h * wh) * K;
        const float mv = (g == 2) ? tanhf(v) : 1.f / (1.f + expf(-v));
        const float fv = __shfl(mv, gbase + 0);
        const float iv = __shfl(mv, gbase + 1);
        const float gv = __shfl(mv, gbase + 2);
        const float ov = __shfl(mv, gbase + 3);
        c = fv * c + iv * gv;
        h = ov * tanhf(c);
        if (g == 0) hseq[b * TT + t] = h;
    }
    if (g == 0) { hfin[b] = h; cfin[b] = c; }
}

// Kernel 3: broadcast scalars to [B,T,H] ++ [B,H] ++ [B,H]
__global__ __launch_bounds__(256) void qlstm_bcast(
    const float* __restrict__ hseq, const float* __restrict__ hfin,
    const float* __restrict__ cfin, float4* __restrict__ out)
{
    const int idx = blockIdx.x * 256 + threadIdx.x;  // float4 index
    const int e   = idx * 4;
    float v;
    if (e < BB * TT * HH)                 v = hseq[e >> 8];
    else if (e < BB * TT * HH + BB * HH)  v = hfin[(e - BB * TT * HH) >> 8];
    else                                  v = cfin[(e - BB * TT * HH - BB * HH) >> 8];
    out[idx] = make_float4(v, v, v, v);
}

extern "C" void kernel_launch(void* const* d_in, const int* in_sizes, int n_in,
                              void* d_out, int out_size, void* d_ws, size_t ws_size,
                              hipStream_t stream) {
    // setup_inputs() dict order:
    // 0 inputs, then per gate n in [f,i,g,o]: W n, b n, rx n, rz n
    const float* x   = (const float*)d_in[0];
    const float* Wf  = (const float*)d_in[1];
    const float* bf  = (const float*)d_in[2];
    const float* rxf = (const float*)d_in[3];
    const float* Wi  = (const float*)d_in[5];
    const float* bi  = (const float*)d_in[6];
    const float* rxi = (const float*)d_in[7];
    const float* Wg  = (const float*)d_in[9];
    const float* bg  = (const float*)d_in[10];
    const float* rxg = (const float*)d_in[11];
    const float* Wo  = (const float*)d_in[13];
    const float* bo  = (const float*)d_in[14];
    const float* rxo = (const float*)d_in[15];
    // rz params provably drop out of <Z> — unused.

    char*   ws   = (char*)d_ws;
    float4* ax   = (float4*)ws;
    float*  hseq = (float*)(ws + 131072);
    float*  hfin = (float*)(ws + 163840);
    float*  cfin = (float*)(ws + 164864);

    qlstm_gemv<<<2048, 256, 0, stream>>>(x, Wf, bf, Wi, bi, Wg, bg, Wo, bo, ax);
    qlstm_scan<<<4, 256, 0, stream>>>(Wf, rxf, Wi, rxi, Wg, rxg, Wo, rxo,
                                      (const float*)ax, hseq, hfin, cfin);
    qlstm_bcast<<<2176, 256, 0, stream>>>(hseq, hfin, cfin, (float4*)d_out);
}